// Round 1
// baseline (293.642 us; speedup 1.0000x reference)
//
#include <hip/hip_runtime.h>

#define NSZ 192
#define N1  191
#define TW  64
#define TH  8
#define TD  16
#define LROWS 11              // TH+3 rows: h0-1 .. h0+9
#define PADW  80              // lds row floats, covers global cols w0-1 .. w0+78
#define CHSZ  (LROWS*PADW)    // 880
#define SLOTSZ (3*CHSZ)       // 2640 floats per slice slot
#define NTHREADS 128

// Stage one y-slice (all 3 channels, rows h0-1..h0+9, cols w0-1..w0+78, clamped)
// into LDS slot. Coalesced scalar loads; LDS offset == linear element index.
__device__ __forceinline__ void stage_slice(const float* __restrict__ y,
                                            float* __restrict__ lds,
                                            int s, int slot, int h0, int w0, int tid) {
    if (s > N1) return;  // uniform
    float* dst = lds + slot * SLOTSZ;
    #pragma unroll 1
    for (int e = tid; e < SLOTSZ; e += NTHREADS) {
        int ch  = e / CHSZ;
        int r2  = e - ch * CHSZ;
        int row = r2 / PADW;
        int col = r2 - row * PADW;
        int gr = h0 - 1 + row; gr = gr < 0 ? 0 : (gr > N1 ? N1 : gr);
        int gc = w0 - 1 + col; gc = gc < 0 ? 0 : (gc > N1 ? N1 : gc);
        dst[e] = y[ch * (NSZ*NSZ*NSZ) + s * (NSZ*NSZ) + gr * NSZ + gc];
    }
}

__global__ __launch_bounds__(NTHREADS, 2)
void jac_kernel(const float* __restrict__ y, float* __restrict__ out) {
    __shared__ __align__(16) float lds[3 * SLOTSZ];

    const int tx = threadIdx.x;          // 0..15 (k-group of 4)
    const int ty = threadIdx.y;          // 0..7  (output row)
    const int tid = ty * 16 + tx;
    const int w0 = blockIdx.x * TW;
    const int h0 = blockIdx.y * TH;
    const int d0 = blockIdx.z * TD;
    const int j  = h0 + ty;              // this thread's output row
    const int k0 = w0 + tx * 4;          // first of 4 owned output cols

    // diff-position validity masks: positions gk = k0-1+p, rows gr = j-1+r
    float mrow[3][6];
    #pragma unroll
    for (int r = 0; r < 3; ++r) {
        int gr = j - 1 + r;
        float rv = (gr >= 0 && gr < N1) ? 1.f : 0.f;
        #pragma unroll
        for (int p = 0; p < 6; ++p) {
            int gk = k0 - 1 + p;
            mrow[r][p] = (gk >= 0 && gk < N1) ? rv : 0.f;
        }
    }

    // d-direction running box sum: f(d=i-1) = PS + acc(i); PS' = T1 + acc; T1' = acc
    float PS[36], T1[36];
    #pragma unroll
    for (int t = 0; t < 36; ++t) { PS[t] = 0.f; T1[t] = 0.f; }

    // prologue: stage slices d0-1 (if exists) and d0
    if (d0 >= 1) stage_slice(y, lds, d0 - 1, (d0 + 2) % 3, h0, w0, tid);
    stage_slice(y, lds, d0, d0 % 3, h0, w0, tid);
    __syncthreads();

    const int ltx4 = tx * 4;

    for (int ii = 0; ii < TD + 2; ++ii) {
        const int i  = d0 - 1 + ii;          // diff-slice index
        const int sA = ((i % 3) + 3) % 3;    // slot of slice i
        const int sB = (sA + 1) % 3;         // slot of slice i+1

        // stage slice i+2 into the third slot (not read this step) — overlaps compute
        if (ii <= TD) stage_slice(y, lds, i + 2, (sA + 2) % 3, h0, w0, tid);

        float acc[36];
        #pragma unroll
        for (int t = 0; t < 36; ++t) acc[t] = 0.f;

        if (i >= 0 && i <= N1 - 1) {         // uniform: slice i inside diff volume
            #pragma unroll
            for (int c = 0; c < 3; ++c) {
                const float* bA = lds + sA * SLOTSZ + c * CHSZ + ltx4;
                const float* bB = lds + sB * SLOTSZ + c * CHSZ + ltx4;
                float Y0[8], Y1[8], Z0[8];
                // Y0 = row j-1 @ slice i  (global cols k0-1..k0+6)
                *(float4*)&Y0[0] = *(const float4*)&bA[(ty + 0) * PADW];
                *(float4*)&Y0[4] = *(const float4*)&bA[(ty + 0) * PADW + 4];
                #pragma unroll
                for (int r = 0; r < 3; ++r) {    // sW rows gr = j-1+r
                    *(float4*)&Y1[0] = *(const float4*)&bA[(ty + r + 1) * PADW];
                    *(float4*)&Y1[4] = *(const float4*)&bA[(ty + r + 1) * PADW + 4];
                    *(float4*)&Z0[0] = *(const float4*)&bB[(ty + r) * PADW];
                    *(float4*)&Z0[4] = *(const float4*)&bB[(ty + r) * PADW + 4];

                    float dxv[6], dyv[6], dzv[6];
                    #pragma unroll
                    for (int p = 0; p < 6; ++p) {
                        float m = mrow[r][p];
                        dxv[p] = fabsf(Y1[p]   - Y0[p]) * m;   // H-diff (ref dx)
                        dyv[p] = fabsf(Z0[p]   - Y0[p]) * m;   // D-diff (ref dy)
                        dzv[p] = fabsf(Y0[p+1] - Y0[p]) * m;   // W-diff (ref dz)
                    }
                    #pragma unroll
                    for (int q = 0; q < 4; ++q) {
                        acc[(c*3+0)*4+q] += dxv[q] + dxv[q+1] + dxv[q+2];
                        acc[(c*3+1)*4+q] += dyv[q] + dyv[q+1] + dyv[q+2];
                        acc[(c*3+2)*4+q] += dzv[q] + dzv[q+1] + dzv[q+2];
                    }
                    #pragma unroll
                    for (int p = 0; p < 8; ++p) Y0[p] = Y1[p];
                }
            }
        }

        float f[36];
        #pragma unroll
        for (int t = 0; t < 36; ++t) {
            f[t]  = PS[t] + acc[t];
            PS[t] = T1[t] + acc[t];
            T1[t] = acc[t];
        }

        const int d = i - 1;
        if (d >= d0 && d < d0 + TD && d <= N1 - 1 && j < N1) {
            const float s27 = 1.f / 27.f;
            #pragma unroll
            for (int q = 0; q < 4; ++q) {
                if (k0 + q < N1) {
                    float axx = f[(1*3+0)*4+q]*s27, axy = f[(1*3+1)*4+q]*s27, axz = f[(1*3+2)*4+q]*s27;
                    float ayx = f[(0*3+0)*4+q]*s27, ayy = f[(0*3+1)*4+q]*s27, ayz = f[(0*3+2)*4+q]*s27;
                    float azx = f[(2*3+0)*4+q]*s27, azy = f[(2*3+1)*4+q]*s27, azz = f[(2*3+2)*4+q]*s27;
                    float ee = ayy + 1.f, zz = azz + 1.f;
                    float J = (axx + 1.f) * (ee*zz - ayz*azy)
                            - axy * (ayx*zz - ayz*azx)
                            + axz * (ayx*azy - ee*azx);
                    out[(d * N1 + j) * N1 + (k0 + q)] = J;
                }
            }
        }
        __syncthreads();
    }
}

extern "C" void kernel_launch(void* const* d_in, const int* in_sizes, int n_in,
                              void* d_out, int out_size, void* d_ws, size_t ws_size,
                              hipStream_t stream) {
    const float* y = (const float*)d_in[0];
    float* out = (float*)d_out;
    dim3 grid(3, 24, 12);     // w-tiles, h-tiles, d-chunks
    dim3 block(16, 8, 1);
    jac_kernel<<<grid, block, 0, stream>>>(y, out);
}

// Round 2
// 115.819 us; speedup vs baseline: 2.5353x; 2.5353x over previous
//
#include <hip/hip_runtime.h>

#define NSZ 192
#define N1  191
#define TW  64
#define TH  8
#define TD  8
#define LROWS 11              // TH+3 rows: h0-1 .. h0+9
#define PADW  72              // lds row floats, covers global cols w0-1 .. w0+70
#define CHSZ  (LROWS*PADW)    // 792
#define SLOTSZ (3*CHSZ)       // 2376 floats per slice slot
#define NTHREADS 256

// Stage one y-slice (all 3 channels, rows h0-1..h0+9, cols w0-1..w0+70, clamped)
// into LDS slot. Coalesced scalar loads; LDS offset == linear element index.
__device__ __forceinline__ void stage_slice(const float* __restrict__ y,
                                            float* __restrict__ lds,
                                            int s, int slot, int h0, int w0, int tid) {
    if (s > N1) return;  // uniform
    float* dst = lds + slot * SLOTSZ;
    #pragma unroll 1
    for (int e = tid; e < SLOTSZ; e += NTHREADS) {
        int ch  = e / CHSZ;
        int r2  = e - ch * CHSZ;
        int row = r2 / PADW;
        int col = r2 - row * PADW;
        int gr = h0 - 1 + row; gr = gr < 0 ? 0 : (gr > N1 ? N1 : gr);
        int gc = w0 - 1 + col; gc = gc < 0 ? 0 : (gc > N1 ? N1 : gc);
        dst[e] = y[ch * (NSZ*NSZ*NSZ) + s * (NSZ*NSZ) + gr * NSZ + gc];
    }
}

__global__ __launch_bounds__(NTHREADS)
void jac_kernel(const float* __restrict__ y, float* __restrict__ out) {
    __shared__ __align__(16) float lds[3 * SLOTSZ];

    const int tx = threadIdx.x;          // 0..31 (owns 2 output cols)
    const int ty = threadIdx.y;          // 0..7  (output row)
    const int tid = ty * 32 + tx;
    const int w0 = blockIdx.x * TW;
    const int h0 = blockIdx.y * TH;
    const int d0 = blockIdx.z * TD;
    const int j  = h0 + ty;              // this thread's output row
    const int k0 = w0 + tx * 2;          // first of 2 owned output cols

    // diff-position validity masks: positions gk = k0-1+p, rows gr = j-1+r
    float mrow[3][4];
    #pragma unroll
    for (int r = 0; r < 3; ++r) {
        int gr = j - 1 + r;
        float rv = (gr >= 0 && gr < N1) ? 1.f : 0.f;
        #pragma unroll
        for (int p = 0; p < 4; ++p) {
            int gk = k0 - 1 + p;
            mrow[r][p] = (gk >= 0 && gk < N1) ? rv : 0.f;
        }
    }

    // d-direction running box sum: f(d=i-1) = PS + acc(i); PS' = T1 + acc; T1' = acc
    float PS[18], T1[18];
    #pragma unroll
    for (int t = 0; t < 18; ++t) { PS[t] = 0.f; T1[t] = 0.f; }

    // prologue: stage slices d0-1 (if exists) and d0
    if (d0 >= 1) stage_slice(y, lds, d0 - 1, (d0 + 2) % 3, h0, w0, tid);
    stage_slice(y, lds, d0, d0 % 3, h0, w0, tid);
    __syncthreads();

    const int ltx2 = tx * 2;

    for (int ii = 0; ii < TD + 2; ++ii) {
        const int i  = d0 - 1 + ii;          // diff-slice index
        const int sA = ((i % 3) + 3) % 3;    // slot of slice i
        const int sB = (sA + 1) % 3;         // slot of slice i+1

        // stage slice i+2 into the third slot (not read this step) — overlaps compute
        if (ii <= TD) stage_slice(y, lds, i + 2, (sA + 2) % 3, h0, w0, tid);

        float acc[18];
        #pragma unroll
        for (int t = 0; t < 18; ++t) acc[t] = 0.f;

        if (i >= 0 && i <= N1 - 1) {         // uniform: slice i inside diff volume
            #pragma unroll
            for (int c = 0; c < 3; ++c) {
                const float* bA = lds + sA * SLOTSZ + c * CHSZ + ltx2;
                const float* bB = lds + sB * SLOTSZ + c * CHSZ + ltx2;
                float Y0[6], Y1[6], Z0[4];
                // Y0 = row j-1 @ slice i  (global cols k0-1..k0+4)
                *(float2*)&Y0[0] = *(const float2*)&bA[(ty + 0) * PADW];
                *(float2*)&Y0[2] = *(const float2*)&bA[(ty + 0) * PADW + 2];
                *(float2*)&Y0[4] = *(const float2*)&bA[(ty + 0) * PADW + 4];
                #pragma unroll
                for (int r = 0; r < 3; ++r) {    // diff rows gr = j-1+r
                    *(float2*)&Y1[0] = *(const float2*)&bA[(ty + r + 1) * PADW];
                    *(float2*)&Y1[2] = *(const float2*)&bA[(ty + r + 1) * PADW + 2];
                    *(float2*)&Y1[4] = *(const float2*)&bA[(ty + r + 1) * PADW + 4];
                    *(float2*)&Z0[0] = *(const float2*)&bB[(ty + r) * PADW];
                    *(float2*)&Z0[2] = *(const float2*)&bB[(ty + r) * PADW + 2];

                    float dxv[4], dyv[4], dzv[4];
                    #pragma unroll
                    for (int p = 0; p < 4; ++p) {
                        float m = mrow[r][p];
                        dxv[p] = fabsf(Y1[p]   - Y0[p]) * m;   // H-diff (ref dx)
                        dyv[p] = fabsf(Z0[p]   - Y0[p]) * m;   // D-diff (ref dy)
                        dzv[p] = fabsf(Y0[p+1] - Y0[p]) * m;   // W-diff (ref dz)
                    }
                    #pragma unroll
                    for (int q = 0; q < 2; ++q) {
                        acc[(c*3+0)*2+q] += dxv[q] + dxv[q+1] + dxv[q+2];
                        acc[(c*3+1)*2+q] += dyv[q] + dyv[q+1] + dyv[q+2];
                        acc[(c*3+2)*2+q] += dzv[q] + dzv[q+1] + dzv[q+2];
                    }
                    #pragma unroll
                    for (int p = 0; p < 6; ++p) Y0[p] = Y1[p];
                }
            }
        }

        float f[18];
        #pragma unroll
        for (int t = 0; t < 18; ++t) {
            f[t]  = PS[t] + acc[t];
            PS[t] = T1[t] + acc[t];
            T1[t] = acc[t];
        }

        const int d = i - 1;
        if (d >= d0 && d < d0 + TD && d <= N1 - 1 && j < N1) {
            const float s27 = 1.f / 27.f;
            #pragma unroll
            for (int q = 0; q < 2; ++q) {
                if (k0 + q < N1) {
                    float axx = f[(1*3+0)*2+q]*s27, axy = f[(1*3+1)*2+q]*s27, axz = f[(1*3+2)*2+q]*s27;
                    float ayx = f[(0*3+0)*2+q]*s27, ayy = f[(0*3+1)*2+q]*s27, ayz = f[(0*3+2)*2+q]*s27;
                    float azx = f[(2*3+0)*2+q]*s27, azy = f[(2*3+1)*2+q]*s27, azz = f[(2*3+2)*2+q]*s27;
                    float ee = ayy + 1.f, zz = azz + 1.f;
                    float J = (axx + 1.f) * (ee*zz - ayz*azy)
                            - axy * (ayx*zz - ayz*azx)
                            + axz * (ayx*azy - ee*azx);
                    out[(d * N1 + j) * N1 + (k0 + q)] = J;
                }
            }
        }
        __syncthreads();
    }
}

extern "C" void kernel_launch(void* const* d_in, const int* in_sizes, int n_in,
                              void* d_out, int out_size, void* d_ws, size_t ws_size,
                              hipStream_t stream) {
    const float* y = (const float*)d_in[0];
    float* out = (float*)d_out;
    dim3 grid(3, 24, 24);     // w-tiles, h-tiles, d-chunks
    dim3 block(32, 8, 1);
    jac_kernel<<<grid, block, 0, stream>>>(y, out);
}

// Round 3
// 62.029 us; speedup vs baseline: 4.7339x; 1.8672x over previous
//
#include <hip/hip_runtime.h>

#define NSZ   192
#define NSZ2  (NSZ*NSZ)
#define NSZ3  (NSZ*NSZ*NSZ)
#define N1    191
#define TW    64
#define TH    8
#define TD    8
#define LROWS 11
#define PADW  72              // floats per LDS row; LDS col c <-> global col w0-4+c
#define ROWF4 18              // float4 per row
#define NROWS 33              // 3 ch * 11 rows
#define SLOTF4 (NROWS*ROWF4)  // 594 float4 per slice slot
#define SLOTF  (SLOTF4*4)     // 2376 floats
#define NTHREADS 256

__device__ __forceinline__ void ld3f2(float* d, const float* p) {
    *(float2*)&d[0] = *(const float2*)&p[0];
    *(float2*)&d[2] = *(const float2*)&p[2];
    *(float2*)&d[4] = *(const float2*)&p[4];
}

__global__ __launch_bounds__(NTHREADS)
void jac_kernel(const float* __restrict__ y, float* __restrict__ out) {
    __shared__ __align__(16) float lds[3 * SLOTF];

    const int tx = threadIdx.x;          // 0..31, owns 2 output cols
    const int ty = threadIdx.y;          // 0..7, owns 1 output row
    const int tid = ty * 32 + tx;
    const int w0 = blockIdx.x * TW;
    const int h0 = blockIdx.y * TH;
    const int d0 = blockIdx.z * TD;
    const int j  = h0 + ty;
    const int k0 = w0 + 2 * tx;

    // diff-position validity masks (positions gk = k0-1+p, diff rows gr = j-1+r)
    float mrow[3][4];
    #pragma unroll
    for (int r = 0; r < 3; ++r) {
        int gr = j - 1 + r;
        float rv = (gr >= 0 && gr < N1) ? 1.f : 0.f;
        #pragma unroll
        for (int p = 0; p < 4; ++p) {
            int gk = k0 - 1 + p;
            mrow[r][p] = (gk >= 0 && gk < N1) ? rv : 0.f;
        }
    }

    // ---- staging precompute: per-thread float4 elements e4 = tid + k*256 ----
    const bool has3 = (tid < SLOTF4 - 2 * NTHREADS);   // 594-512 = 82
    int goff[3];
    #pragma unroll
    for (int k = 0; k < 3; ++k) {
        int e4 = tid + k * NTHREADS;
        int e4c = e4 < SLOTF4 ? e4 : 0;
        int rowidx = e4c / ROWF4;
        int m   = e4c - rowidx * ROWF4;
        int ch  = rowidx / LROWS;
        int row = rowidx - ch * LROWS;
        int gr = h0 - 1 + row; gr = gr < 0 ? 0 : (gr > N1 ? N1 : gr);
        int c4 = w0 - 4 + 4 * m; c4 = c4 < 0 ? 0 : (c4 > NSZ - 4 ? NSZ - 4 : c4);
        goff[k] = ch * NSZ3 + gr * NSZ + c4;
    }

    // d-direction running box sum: f(d=i-1) = PS + acc(i); PS' = T1 + acc; T1' = acc
    float PS[18], T1[18];
    #pragma unroll
    for (int t = 0; t < 18; ++t) { PS[t] = 0.f; T1[t] = 0.f; }

    // ---- prologue: stage slices d0-1 (if exists) and d0 ----
    {
        float4 s0a, s0b, s0c, s1a, s1b, s1c;
        const bool p0 = (d0 >= 1);
        if (p0) {
            const float* b = y + (size_t)(d0 - 1) * NSZ2;
            s0a = *(const float4*)&b[goff[0]];
            s0b = *(const float4*)&b[goff[1]];
            if (has3) s0c = *(const float4*)&b[goff[2]];
        }
        {
            const float* b = y + (size_t)d0 * NSZ2;
            s1a = *(const float4*)&b[goff[0]];
            s1b = *(const float4*)&b[goff[1]];
            if (has3) s1c = *(const float4*)&b[goff[2]];
        }
        if (p0) {
            float* d = lds + ((d0 + 2) % 3) * SLOTF;
            *(float4*)&d[tid * 4] = s0a;
            *(float4*)&d[(tid + 256) * 4] = s0b;
            if (has3) *(float4*)&d[(tid + 512) * 4] = s0c;
        }
        {
            float* d = lds + (d0 % 3) * SLOTF;
            *(float4*)&d[tid * 4] = s1a;
            *(float4*)&d[(tid + 256) * 4] = s1b;
            if (has3) *(float4*)&d[(tid + 512) * 4] = s1c;
        }
    }
    __syncthreads();

    int sA = (d0 + 2) % 3;               // slot of slice i = d0-1

    for (int ii = 0; ii < TD + 2; ++ii) {
        const int i  = d0 - 1 + ii;      // diff-slice index
        const int sB = sA == 2 ? 0 : sA + 1;
        const int sC = sB == 2 ? 0 : sB + 1;

        // ---- phase 1: issue global loads for slice i+2 (lands in sC) ----
        const bool doStage = (ii <= TD) && (i + 2 <= N1);
        float4 g0, g1, g2;
        if (doStage) {
            const float* b = y + (size_t)(i + 2) * NSZ2;
            g0 = *(const float4*)&b[goff[0]];
            g1 = *(const float4*)&b[goff[1]];
            if (has3) g2 = *(const float4*)&b[goff[2]];
        }

        // ---- phase 2: compute on slices i (sA) and i+1 (sB) ----
        float acc[18];
        #pragma unroll
        for (int t = 0; t < 18; ++t) acc[t] = 0.f;

        if (i >= 0 && i < N1) {          // uniform
            #pragma unroll
            for (int c = 0; c < 3; ++c) {
                const float* pA = lds + sA * SLOTF + (c * LROWS + ty) * PADW + 2 * tx + 2;
                const float* pB = lds + sB * SLOTF + (c * LROWS + ty) * PADW + 2 * tx + 2;
                // windows: idx p' <-> global col k0-2+p'
                float Y0[6], Y1[6], Z0[6];
                ld3f2(Y0, pA);                       // value row j-1 @ slice i
                #pragma unroll
                for (int r = 0; r < 3; ++r) {        // diff rows gr = j-1+r
                    ld3f2(Y1, pA + (r + 1) * PADW);  // value row j+r @ slice i
                    ld3f2(Z0, pB + r * PADW);        // value row j-1+r @ slice i+1
                    float dxv[4], dyv[4], dzv[4];
                    #pragma unroll
                    for (int p = 0; p < 4; ++p) {
                        float m = mrow[r][p];
                        dxv[p] = fabsf(Y1[p + 1] - Y0[p + 1]) * m;   // H-diff
                        dyv[p] = fabsf(Z0[p + 1] - Y0[p + 1]) * m;   // D-diff
                        dzv[p] = fabsf(Y0[p + 2] - Y0[p + 1]) * m;   // W-diff
                    }
                    #pragma unroll
                    for (int q = 0; q < 2; ++q) {
                        acc[(c * 3 + 0) * 2 + q] += dxv[q] + dxv[q + 1] + dxv[q + 2];
                        acc[(c * 3 + 1) * 2 + q] += dyv[q] + dyv[q + 1] + dyv[q + 2];
                        acc[(c * 3 + 2) * 2 + q] += dzv[q] + dzv[q + 1] + dzv[q + 2];
                    }
                    #pragma unroll
                    for (int p = 0; p < 6; ++p) Y0[p] = Y1[p];
                }
            }
        }

        // ---- ring update + output ----
        float f[18];
        #pragma unroll
        for (int t = 0; t < 18; ++t) {
            f[t]  = PS[t] + acc[t];
            PS[t] = T1[t] + acc[t];
            T1[t] = acc[t];
        }

        const int d = i - 1;
        if (ii >= 2 && d < N1 && j < N1) {
            const float s27 = 1.f / 27.f;
            #pragma unroll
            for (int q = 0; q < 2; ++q) {
                if (k0 + q < N1) {
                    float axx = f[(1*3+0)*2+q]*s27, axy = f[(1*3+1)*2+q]*s27, axz = f[(1*3+2)*2+q]*s27;
                    float ayx = f[(0*3+0)*2+q]*s27, ayy = f[(0*3+1)*2+q]*s27, ayz = f[(0*3+2)*2+q]*s27;
                    float azx = f[(2*3+0)*2+q]*s27, azy = f[(2*3+1)*2+q]*s27, azz = f[(2*3+2)*2+q]*s27;
                    float ee = ayy + 1.f, zz = azz + 1.f;
                    float J = (axx + 1.f) * (ee*zz - ayz*azy)
                            - axy * (ayx*zz - ayz*azx)
                            + axz * (ayx*azy - ee*azx);
                    out[(d * N1 + j) * N1 + (k0 + q)] = J;
                }
            }
        }

        // ---- phase 3: write staged slice i+2 into sC, then barrier ----
        if (doStage) {
            float* dst = lds + sC * SLOTF;
            *(float4*)&dst[tid * 4] = g0;
            *(float4*)&dst[(tid + 256) * 4] = g1;
            if (has3) *(float4*)&dst[(tid + 512) * 4] = g2;
        }
        __syncthreads();

        sA = sB;
    }
}

extern "C" void kernel_launch(void* const* d_in, const int* in_sizes, int n_in,
                              void* d_out, int out_size, void* d_ws, size_t ws_size,
                              hipStream_t stream) {
    const float* y = (const float*)d_in[0];
    float* out = (float*)d_out;
    dim3 grid(3, 24, 24);     // w-tiles, h-tiles, d-chunks
    dim3 block(32, 8, 1);
    jac_kernel<<<grid, block, 0, stream>>>(y, out);
}